// Round 19
// baseline (295.317 us; speedup 1.0000x reference)
//
#include <hip/hip_runtime.h>
#include <hip/hip_bf16.h>
#include <math.h>

#define NNODES 50000
#define NEDGES 800000
#define DMODEL 128
#define QK_SCALE 0.25f  // 1/sqrt(16)
#define NSB 196         // scan blocks = ceil(NNODES/256)
#define KVROW 384       // bytes per KV row: 128B K-fp8 + 256B V-bf16

typedef float fvec4 __attribute__((ext_vector_type(4)));
typedef float fvec2 __attribute__((ext_vector_type(2)));
typedef short sv8  __attribute__((ext_vector_type(8)));   // 8 bf16 in 4 VGPRs

__device__ __forceinline__ unsigned short f2bf(float f) {
    unsigned int u = __float_as_uint(f);
    unsigned int r = (u + 0x7FFFu + ((u >> 16) & 1u)) >> 16;   // RNE
    return (unsigned short)r;
}

__device__ __forceinline__ float bf2f(unsigned short b) {
    return __uint_as_float(((unsigned int)b) << 16);
}

// convert 8 packed bf16 (one uint4) -> two fvec4 (memory order)
__device__ __forceinline__ void bf8_to_f32(uint4 u, fvec4& lo, fvec4& hi) {
    lo.x = __uint_as_float(u.x << 16); lo.y = __uint_as_float(u.x & 0xFFFF0000u);
    lo.z = __uint_as_float(u.y << 16); lo.w = __uint_as_float(u.y & 0xFFFF0000u);
    hi.x = __uint_as_float(u.z << 16); hi.y = __uint_as_float(u.z & 0xFFFF0000u);
    hi.z = __uint_as_float(u.w << 16); hi.w = __uint_as_float(u.w & 0xFFFF0000u);
}

// convert 4 packed fp8 (one uint) -> fvec4 via HW cvt (byte0 -> .x)
__device__ __forceinline__ void fp8x4_to_f32(unsigned int u, fvec4& k) {
    fvec2 lo = __builtin_amdgcn_cvt_pk_f32_fp8(u, false);
    fvec2 hi = __builtin_amdgcn_cvt_pk_f32_fp8(u, true);
    k.x = lo.x; k.y = lo.y; k.z = hi.x; k.w = hi.y;
}

__device__ __forceinline__ unsigned char f2fp8(float v) {
    unsigned int pk = (unsigned int)__builtin_amdgcn_cvt_pk_fp8_f32(v, v, 0, false);
    return (unsigned char)(pk & 0xFFu);
}

// ---------------------------------------------------------------------------
// prep: X f32 -> Xb bf16; Wq/Wk/Wv/Wo f32 [k][n] -> Wb bf16 TRANSPOSED
// [w][n][k]; also zeroes cnt.
// ---------------------------------------------------------------------------
__global__ __launch_bounds__(256) void prep_kernel(const float* __restrict__ X,
                                                   const float* __restrict__ Wq,
                                                   const float* __restrict__ Wk,
                                                   const float* __restrict__ Wv,
                                                   const float* __restrict__ Wo,
                                                   unsigned short* __restrict__ Xb,
                                                   unsigned short* __restrict__ Wb,
                                                   int* __restrict__ cnt) {
    int i = blockIdx.x * 256 + threadIdx.x;
    if (i < NNODES * 32) {                      // float4 granularity
        float4 v = *(const float4*)&X[(size_t)i * 4];
        ushort4 s;
        s.x = f2bf(v.x); s.y = f2bf(v.y); s.z = f2bf(v.z); s.w = f2bf(v.w);
        *(ushort4*)&Xb[(size_t)i * 4] = s;
    } else {
        int j = i - NNODES * 32;
        if (j < 4 * 16384) {
            int w = j >> 14, rem = j & 16383;
            int n = rem >> 7, k = rem & 127;
            const float* src = (w == 0) ? Wq : (w == 1) ? Wk : (w == 2) ? Wv : Wo;
            Wb[j] = f2bf(src[k * 128 + n]);
        } else {
            int c = j - 4 * 16384;
            if (c < NNODES) cnt[c] = 0;
        }
    }
}

// ---------------------------------------------------------------------------
// QKV projection via bf16 MFMA (blockIdx.y = 0/1/2 -> Q/K/V)
// KV row = 384B: [K fp8: byte = col][Vp0/Vp1 bf16 part-interleaved at +128B]
//   V byte off = 128 + ((col&8)<<4) + ((col>>4)<<4) + ((col&7)<<1)
// ---------------------------------------------------------------------------
__global__ __launch_bounds__(256) void gemm_qkv(const unsigned short* __restrict__ Xb,
                                                const unsigned short* __restrict__ Wb,
                                                const float* __restrict__ bq,
                                                const float* __restrict__ bk,
                                                const float* __restrict__ bv,
                                                unsigned short* __restrict__ Qb,
                                                unsigned char* __restrict__ KVb,
                                                int M) {
    __shared__ unsigned short Als[64 * 128];
    __shared__ unsigned short Bls[128 * 128];
    char* Ac = (char*)Als;
    char* Bc = (char*)Bls;

    int z = blockIdx.y;
    int r0 = blockIdx.x * 64;
    int tid = threadIdx.x;
    int wave = tid >> 6, lane = tid & 63;

    const char* Wsrc = (const char*)(Wb + (size_t)z * 16384);

    #pragma unroll
    for (int p = 0; p < 4; ++p) {
        int o = p * 4096 + tid * 16;
        int r = o >> 8;
        int gr = r0 + r; if (gr >= M) gr = M - 1;
        uint4 v = *(const uint4*)((const char*)Xb + (size_t)gr * 256 + (o & 255));
        *(uint4*)(Ac + r * 256 + ((o & 255) ^ ((r & 7) << 4))) = v;
    }
    #pragma unroll
    for (int p = 0; p < 8; ++p) {
        int o = p * 4096 + tid * 16;
        int r = o >> 8;
        uint4 v = *(const uint4*)(Wsrc + o);
        *(uint4*)(Bc + (o ^ ((r & 7) << 4))) = v;
    }
    __syncthreads();

    fvec4 acc[8] = {};
    int arow = wave * 16 + (lane & 15);
    int kchunk = (lane >> 4) * 16;

    #pragma unroll
    for (int ks = 0; ks < 4; ++ks) {
        int ain = (ks * 64 + kchunk) ^ ((arow & 7) << 4);
        sv8 af = *(const sv8*)(Ac + arow * 256 + ain);
        #pragma unroll
        for (int cf = 0; cf < 8; ++cf) {
            int brow = cf * 16 + (lane & 15);
            int bin = (ks * 64 + kchunk) ^ ((brow & 7) << 4);
            sv8 bf = *(const sv8*)(Bc + brow * 256 + bin);
            acc[cf] = __builtin_amdgcn_mfma_f32_16x16x32_bf16(af, bf, acc[cf], 0, 0, 0);
        }
    }

    const float* bias = (z == 0) ? bq : (z == 1) ? bk : bv;

    #pragma unroll
    for (int cf = 0; cf < 8; ++cf) {
        int col_ = cf * 16 + (lane & 15);
        float b = bias[col_];
        #pragma unroll
        for (int r = 0; r < 4; ++r) {
            int gr = r0 + wave * 16 + ((lane >> 4) * 4) + r;
            if (gr < M) {
                float val = acc[cf][r] + b;
                if (z == 0) {
                    Qb[(size_t)gr * 128 + col_] = f2bf(val);
                } else if (z == 1) {
                    KVb[(size_t)gr * KVROW + col_] = f2fp8(val);   // K: byte = col
                } else {
                    int boff = 128 + ((col_ & 8) << 4) + ((col_ >> 4) << 4) + ((col_ & 7) << 1);
                    *(unsigned short*)(KVb + (size_t)gr * KVROW + boff) = f2bf(val);
                }
            }
        }
    }
}

// ---------------------------------------------------------------------------
// output projection via bf16 MFMA: out f32 = aggb bf16 @ Wo^T bf16 + bo
// ---------------------------------------------------------------------------
__global__ __launch_bounds__(256) void gemm_out(const unsigned short* __restrict__ Ab,
                                                const unsigned short* __restrict__ Wob,
                                                const float* __restrict__ bo,
                                                float* __restrict__ outp, int M) {
    __shared__ unsigned short Als[64 * 128];
    __shared__ unsigned short Bls[128 * 128];
    char* Ac = (char*)Als;
    char* Bc = (char*)Bls;

    int r0 = blockIdx.x * 64;
    int tid = threadIdx.x;
    int wave = tid >> 6, lane = tid & 63;

    #pragma unroll
    for (int p = 0; p < 4; ++p) {
        int o = p * 4096 + tid * 16;
        int r = o >> 8;
        int gr = r0 + r; if (gr >= M) gr = M - 1;
        uint4 v = *(const uint4*)((const char*)Ab + (size_t)gr * 256 + (o & 255));
        *(uint4*)(Ac + r * 256 + ((o & 255) ^ ((r & 7) << 4))) = v;
    }
    #pragma unroll
    for (int p = 0; p < 8; ++p) {
        int o = p * 4096 + tid * 16;
        int r = o >> 8;
        uint4 v = *(const uint4*)((const char*)Wob + o);
        *(uint4*)(Bc + (o ^ ((r & 7) << 4))) = v;
    }
    __syncthreads();

    fvec4 acc[8] = {};
    int arow = wave * 16 + (lane & 15);
    int kchunk = (lane >> 4) * 16;

    #pragma unroll
    for (int ks = 0; ks < 4; ++ks) {
        int ain = (ks * 64 + kchunk) ^ ((arow & 7) << 4);
        sv8 af = *(const sv8*)(Ac + arow * 256 + ain);
        #pragma unroll
        for (int cf = 0; cf < 8; ++cf) {
            int brow = cf * 16 + (lane & 15);
            int bin = (ks * 64 + kchunk) ^ ((brow & 7) << 4);
            sv8 bf = *(const sv8*)(Bc + brow * 256 + bin);
            acc[cf] = __builtin_amdgcn_mfma_f32_16x16x32_bf16(af, bf, acc[cf], 0, 0, 0);
        }
    }

    #pragma unroll
    for (int cf = 0; cf < 8; ++cf) {
        int col = cf * 16 + (lane & 15);
        float b = bo[col];
        #pragma unroll
        for (int r = 0; r < 4; ++r) {
            int gr = r0 + wave * 16 + ((lane >> 4) * 4) + r;
            if (gr < M) outp[(size_t)gr * 128 + col] = acc[cf][r] + b;
        }
    }
}

// ---------------------------------------------------------------------------
// CSR build: histogram -> scan1 (block sums) -> scan3 (folds scan2: each
// block redundantly prefix-sums the 196 block sums from L2, ~200 adds)
// ---------------------------------------------------------------------------
__global__ __launch_bounds__(256) void hist_kernel(const int* __restrict__ row,
                                                   int* __restrict__ cnt) {
    int e = blockIdx.x * 256 + threadIdx.x;
    if (e < NEDGES) atomicAdd(&cnt[row[e]], 1);
}

__global__ __launch_bounds__(256) void scan1_kernel(const int* __restrict__ cnt,
                                                    int* __restrict__ bsum) {
    __shared__ int red[256];
    int idx = blockIdx.x * 256 + threadIdx.x;
    red[threadIdx.x] = (idx < NNODES) ? cnt[idx] : 0;
    __syncthreads();
    for (int off = 128; off > 0; off >>= 1) {
        if (threadIdx.x < off) red[threadIdx.x] += red[threadIdx.x + off];
        __syncthreads();
    }
    if (threadIdx.x == 0) bsum[blockIdx.x] = red[0];
}

__global__ __launch_bounds__(256) void scan3_kernel(const int* __restrict__ cnt,
                                                    const int* __restrict__ bsum,
                                                    int* __restrict__ offs,
                                                    int* __restrict__ cursor) {
    __shared__ int ps[256];
    __shared__ int ps2[256];
    int t = threadIdx.x;

    // fold of scan2: prefix over the 196 block sums, computed per block
    int bv = (t < NSB) ? bsum[t] : 0;
    ps2[t] = bv;
    __syncthreads();
    for (int off = 1; off < 256; off <<= 1) {
        int x = (t >= off) ? ps2[t - off] : 0;
        __syncthreads();
        ps2[t] += x;
        __syncthreads();
    }
    int bpre = (blockIdx.x == 0) ? 0 : ps2[blockIdx.x - 1];

    int idx = blockIdx.x * 256 + t;
    int v = (idx < NNODES) ? cnt[idx] : 0;
    ps[t] = v;
    __syncthreads();
    for (int off = 1; off < 256; off <<= 1) {
        int x = (t >= off) ? ps[t - off] : 0;
        __syncthreads();
        ps[t] += x;
        __syncthreads();
    }
    int ex = ps[t] - v + bpre;
    if (idx < NNODES) { offs[idx] = ex; cursor[idx] = ex; }
    if (idx == NNODES) offs[NNODES] = NEDGES;
}

// ---------------------------------------------------------------------------
// FUSED score kernel (edge order — ef stays a pure HBM STREAM):
// 8 lanes per edge, lane s = head s. Writes bf16 scores at the CSR position.
// ---------------------------------------------------------------------------
__global__ __launch_bounds__(256) void score_scatter(const float* __restrict__ EF,
                                                     const int* __restrict__ row,
                                                     const int* __restrict__ col,
                                                     int* __restrict__ cursor,
                                                     const float* __restrict__ We,
                                                     const float* __restrict__ be,
                                                     const unsigned short* __restrict__ Qb,
                                                     const unsigned char* __restrict__ KVb,
                                                     unsigned short* __restrict__ scores,
                                                     int* __restrict__ col_perm) {
    __shared__ float sWe[8][128];   // [h][d]
    __shared__ float sbe[8];
    for (int i = threadIdx.x; i < 1024; i += 256) {
        int d = i >> 3, h = i & 7;
        sWe[h][d] = We[i];          // We is [d][h] row-major
    }
    if (threadIdx.x < 8) sbe[threadIdx.x] = be[threadIdx.x];
    __syncthreads();

    int g = blockIdx.x * 256 + threadIdx.x;   // NEDGES*8 threads
    int e = g >> 3;
    int s = g & 7;
    if (e >= NEDGES) return;
    int lane = threadIdx.x & 63;

    int r = row[e];
    int c = col[e];

    // claim CSR slot early (latency hides under the streams/gathers below)
    int pos = 0;
    if (s == 0) {
        pos = atomicAdd(&cursor[r], 1);
        col_perm[pos] = c;
    }

    // issue gathers early: Q head-slice (32B) + K fp8 head-slice (16B)
    const uint4* qp = (const uint4*)(Qb + (size_t)r * 128 + s * 16);
    uint4 qu0 = qp[0], qu1 = qp[1];
    uint4 ku = *(const uint4*)(KVb + (size_t)c * KVROW + s * 16);

    const fvec4* efv = (const fvec4*)(EF + (size_t)e * 128);
    float acc[8] = {0.f, 0.f, 0.f, 0.f, 0.f, 0.f, 0.f, 0.f};
    #pragma unroll
    for (int i = 0; i < 4; ++i) {
        int d4 = s + 8 * i;
        fvec4 v = __builtin_nontemporal_load(&efv[d4]);
        #pragma unroll
        for (int h = 0; h < 8; ++h) {
            fvec4 w = *(const fvec4*)&sWe[h][d4 * 4];
            acc[h] += v.x * w.x + v.y * w.y + v.z * w.z + v.w * w.w;
        }
    }

    #pragma unroll
    for (int off = 1; off < 8; off <<= 1)
        #pragma unroll
        for (int h = 0; h < 8; ++h)
            acc[h] += __shfl_xor(acc[h], off);

    // lane-local QK dot for head s
    fvec4 q0, q1, q2, q3, k0, k1, k2, k3;
    bf8_to_f32(qu0, q0, q1);
    bf8_to_f32(qu1, q2, q3);
    fp8x4_to_f32(ku.x, k0);
    fp8x4_to_f32(ku.y, k1);
    fp8x4_to_f32(ku.z, k2);
    fp8x4_to_f32(ku.w, k3);
    fvec4 d4v = q0 * k0 + q1 * k1 + q2 * k2 + q3 * k3;
    float dot = d4v.x + d4v.y + d4v.z + d4v.w;

    pos = __shfl(pos, lane & ~7);             // broadcast from the group's s==0 lane
    scores[(size_t)pos * 8 + s] = f2bf(dot * QK_SCALE + acc[s] + sbe[s]);
}

// ---------------------------------------------------------------------------
// fused online segment softmax + PV. Per slot-edge: bf16 scores (coalesced),
// col_perm, 2 V gathers (bf16, part-interleaved). No K/Q/ef access.
// ---------------------------------------------------------------------------
__global__ __launch_bounds__(256) void fused_agg(const unsigned short* __restrict__ scores,
                                                 const unsigned char* __restrict__ KV,
                                                 const int* __restrict__ col_perm,
                                                 const int* __restrict__ offs,
                                                 unsigned short* __restrict__ aggb) {
    int node = blockIdx.x * 4 + (threadIdx.x >> 6);
    if (node >= NNODES) return;
    int lane = threadIdx.x & 63;
    int slot = lane >> 3;
    int h    = lane & 7;
    int start = offs[node];
    int end   = offs[node + 1];

    float m = -3.0e38f;
    float sum = 0.0f;
    fvec4 a0 = {0.f,0.f,0.f,0.f}, a1 = {0.f,0.f,0.f,0.f};
    fvec4 a2 = {0.f,0.f,0.f,0.f}, a3 = {0.f,0.f,0.f,0.f};

    for (int i = start + slot; i < end; i += 8) {
        int c = col_perm[i];
        float s = bf2f(scores[(size_t)i * 8 + h]);
        const uint4* kp = (const uint4*)(KV + (size_t)c * KVROW);
        uint4 vu0 = kp[8 + h];      // V part0 (bf16)
        uint4 vu1 = kp[16 + h];     // V part1 (bf16)
        fvec4 v0, v1, v2, v3;
        bf8_to_f32(vu0, v0, v1);
        bf8_to_f32(vu1, v2, v3);

        float mn = fmaxf(m, s);
        float corr = __expf(m - mn);
        float w = __expf(s - mn);
        sum = sum * corr + w;
        a0 = a0 * corr + w * v0;
        a1 = a1 * corr + w * v1;
        a2 = a2 * corr + w * v2;
        a3 = a3 * corr + w * v3;
        m = mn;
    }

    #pragma unroll
    for (int off = 8; off < 64; off <<= 1) {
        float mo = __shfl_xor(m, off);
        float so = __shfl_xor(sum, off);
        fvec4 b0, b1, b2, b3;
        b0.x = __shfl_xor(a0.x, off); b0.y = __shfl_xor(a0.y, off);
        b0.z = __shfl_xor(a0.z, off); b0.w = __shfl_xor(a0.w, off);
        b1.x = __shfl_xor(a1.x, off); b1.y = __shfl_xor(a1.y, off);
        b1.z = __shfl_xor(a1.z, off); b1.w = __shfl_xor(a1.w, off);
        b2.x = __shfl_xor(a2.x, off); b2.y = __shfl_xor(a2.y, off);
        b2.z = __shfl_xor(a2.z, off); b2.w = __shfl_xor(a2.w, off);
        b3.x = __shfl_xor(a3.x, off); b3.y = __shfl_xor(a3.y, off);
        b3.z = __shfl_xor(a3.z, off); b3.w = __shfl_xor(a3.w, off);
        float M = fmaxf(m, mo);
        float c1 = __expf(m - M);
        float c2 = __expf(mo - M);
        sum = sum * c1 + so * c2;
        a0 = a0 * c1 + b0 * c2;
        a1 = a1 * c1 + b1 * c2;
        a2 = a2 * c1 + b2 * c2;
        a3 = a3 * c1 + b3 * c2;
        m = M;
    }

    if (slot == 0) {
        float inv = (sum > 0.0f) ? (1.0f / sum) : 0.0f;
        unsigned short* op = aggb + (size_t)node * 128 + h * 16;
        ushort4 s;
        s.x = f2bf(a0.x * inv); s.y = f2bf(a0.y * inv); s.z = f2bf(a0.z * inv); s.w = f2bf(a0.w * inv);
        *(ushort4*)(op + 0) = s;
        s.x = f2bf(a1.x * inv); s.y = f2bf(a1.y * inv); s.z = f2bf(a1.z * inv); s.w = f2bf(a1.w * inv);
        *(ushort4*)(op + 4) = s;
        s.x = f2bf(a2.x * inv); s.y = f2bf(a2.y * inv); s.z = f2bf(a2.z * inv); s.w = f2bf(a2.w * inv);
        *(ushort4*)(op + 8) = s;
        s.x = f2bf(a3.x * inv); s.y = f2bf(a3.y * inv); s.z = f2bf(a3.z * inv); s.w = f2bf(a3.w * inv);
        *(ushort4*)(op + 12) = s;
    }
}

// ---------------------------------------------------------------------------
extern "C" void kernel_launch(void* const* d_in, const int* in_sizes, int n_in,
                              void* d_out, int out_size, void* d_ws, size_t ws_size,
                              hipStream_t stream) {
    const float* node = (const float*)d_in[0];
    const int*   ei   = (const int*)d_in[1];
    const float* ef   = (const float*)d_in[2];
    const float* Wq   = (const float*)d_in[3];
    const float* bq   = (const float*)d_in[4];
    const float* Wk   = (const float*)d_in[5];
    const float* bk   = (const float*)d_in[6];
    const float* Wv   = (const float*)d_in[7];
    const float* bv   = (const float*)d_in[8];
    const float* We   = (const float*)d_in[9];
    const float* be   = (const float*)d_in[10];
    const float* Wo   = (const float*)d_in[11];
    const float* bo   = (const float*)d_in[12];
    float* out = (float*)d_out;

    const int* row = ei;
    const int* col = ei + NEDGES;

    // workspace layout (all 16B-aligned)
    unsigned short* Qb   = (unsigned short*)d_ws;                 // NNODES*128 bf16
    unsigned char*  KVb  = (unsigned char*)(Qb + (size_t)NNODES * 128); // NNODES*384 B
    unsigned short* Xb   = (unsigned short*)(KVb + (size_t)NNODES * KVROW); // NNODES*128 bf16
    unsigned short* Wb   = Xb  + (size_t)NNODES * 128;            // 4*16384 bf16
    unsigned short* aggb = Wb  + 4 * 16384;                       // NNODES*128 bf16
    unsigned short* scores = aggb + (size_t)NNODES * 128;         // NEDGES*8 bf16 (CSR order)
    int*   cnt      = (int*)(scores + (size_t)NEDGES * 8);        // NNODES
    int*   offs     = cnt + NNODES;                               // NNODES+1
    int*   cursor   = offs + NNODES + 1;                          // NNODES
    int*   col_perm = cursor + NNODES;                            // NEDGES
    int*   bsum     = col_perm + NEDGES;                          // 256
    int*   bpre     = bsum + 256;                                 // 256 (unused now)

    prep_kernel<<<(NNODES * 32 + 4 * 16384 + NNODES + 255) / 256, 256, 0, stream>>>(
        node, Wq, Wk, Wv, Wo, Xb, Wb, cnt);
    hist_kernel<<<(NEDGES + 255) / 256, 256, 0, stream>>>(row, cnt);
    scan1_kernel<<<NSB, 256, 0, stream>>>(cnt, bsum);
    scan3_kernel<<<NSB, 256, 0, stream>>>(cnt, bsum, offs, cursor);

    dim3 gqkv((NNODES + 63) / 64, 3);
    gemm_qkv<<<gqkv, 256, 0, stream>>>(Xb, Wb, bq, bk, bv, Qb, KVb, NNODES);

    score_scatter<<<NEDGES * 8 / 256, 256, 0, stream>>>(ef, row, col, cursor, We, be,
                                                        Qb, KVb, scores, col_perm);

    fused_agg<<<(NNODES + 3) / 4, 256, 0, stream>>>(scores, KVb, col_perm, offs, aggb);

    gemm_out<<<(NNODES + 63) / 64, 256, 0, stream>>>(aggb, Wb + 3 * 16384, bo, out, NNODES);
}

// Round 20
// 279.590 us; speedup vs baseline: 1.0563x; 1.0563x over previous
//
#include <hip/hip_runtime.h>
#include <hip/hip_bf16.h>
#include <math.h>

#define NNODES 50000
#define NEDGES 800000
#define DMODEL 128
#define QK_SCALE 0.25f  // 1/sqrt(16)
#define NSB 196         // scan blocks = ceil(NNODES/256)
#define KVROW 384       // bytes per KV row: 128B K-fp8 + 256B V-bf16

typedef float fvec4 __attribute__((ext_vector_type(4)));
typedef float fvec2 __attribute__((ext_vector_type(2)));
typedef short sv8  __attribute__((ext_vector_type(8)));   // 8 bf16 in 4 VGPRs

__device__ __forceinline__ unsigned short f2bf(float f) {
    unsigned int u = __float_as_uint(f);
    unsigned int r = (u + 0x7FFFu + ((u >> 16) & 1u)) >> 16;   // RNE
    return (unsigned short)r;
}

// convert 8 packed bf16 (one uint4) -> two fvec4 (memory order)
__device__ __forceinline__ void bf8_to_f32(uint4 u, fvec4& lo, fvec4& hi) {
    lo.x = __uint_as_float(u.x << 16); lo.y = __uint_as_float(u.x & 0xFFFF0000u);
    lo.z = __uint_as_float(u.y << 16); lo.w = __uint_as_float(u.y & 0xFFFF0000u);
    hi.x = __uint_as_float(u.z << 16); hi.y = __uint_as_float(u.z & 0xFFFF0000u);
    hi.z = __uint_as_float(u.w << 16); hi.w = __uint_as_float(u.w & 0xFFFF0000u);
}

// convert 4 packed fp8 (one uint) -> fvec4 via HW cvt (byte0 -> .x)
__device__ __forceinline__ void fp8x4_to_f32(unsigned int u, fvec4& k) {
    fvec2 lo = __builtin_amdgcn_cvt_pk_f32_fp8(u, false);
    fvec2 hi = __builtin_amdgcn_cvt_pk_f32_fp8(u, true);
    k.x = lo.x; k.y = lo.y; k.z = hi.x; k.w = hi.y;
}

__device__ __forceinline__ unsigned char f2fp8(float v) {
    unsigned int pk = (unsigned int)__builtin_amdgcn_cvt_pk_fp8_f32(v, v, 0, false);
    return (unsigned char)(pk & 0xFFu);
}

// ---------------------------------------------------------------------------
// prep: X f32 -> Xb bf16; Wq/Wk/Wv/Wo f32 [k][n] -> Wb bf16 TRANSPOSED
// [w][n][k]; also zeroes cnt.
// ---------------------------------------------------------------------------
__global__ __launch_bounds__(256) void prep_kernel(const float* __restrict__ X,
                                                   const float* __restrict__ Wq,
                                                   const float* __restrict__ Wk,
                                                   const float* __restrict__ Wv,
                                                   const float* __restrict__ Wo,
                                                   unsigned short* __restrict__ Xb,
                                                   unsigned short* __restrict__ Wb,
                                                   int* __restrict__ cnt) {
    int i = blockIdx.x * 256 + threadIdx.x;
    if (i < NNODES * 32) {                      // float4 granularity
        float4 v = *(const float4*)&X[(size_t)i * 4];
        ushort4 s;
        s.x = f2bf(v.x); s.y = f2bf(v.y); s.z = f2bf(v.z); s.w = f2bf(v.w);
        *(ushort4*)&Xb[(size_t)i * 4] = s;
    } else {
        int j = i - NNODES * 32;
        if (j < 4 * 16384) {
            int w = j >> 14, rem = j & 16383;
            int n = rem >> 7, k = rem & 127;
            const float* src = (w == 0) ? Wq : (w == 1) ? Wk : (w == 2) ? Wv : Wo;
            Wb[j] = f2bf(src[k * 128 + n]);
        } else {
            int c = j - 4 * 16384;
            if (c < NNODES) cnt[c] = 0;
        }
    }
}

// ---------------------------------------------------------------------------
// QKV projection via bf16 MFMA (blockIdx.y = 0/1/2 -> Q/K/V)
// KV row = 384B: [K fp8: byte = col][Vp0/Vp1 bf16 part-interleaved at +128B]
//   V byte off = 128 + ((col&8)<<4) + ((col>>4)<<4) + ((col&7)<<1)
// ---------------------------------------------------------------------------
__global__ __launch_bounds__(256) void gemm_qkv(const unsigned short* __restrict__ Xb,
                                                const unsigned short* __restrict__ Wb,
                                                const float* __restrict__ bq,
                                                const float* __restrict__ bk,
                                                const float* __restrict__ bv,
                                                unsigned short* __restrict__ Qb,
                                                unsigned char* __restrict__ KVb,
                                                int M) {
    __shared__ unsigned short Als[64 * 128];
    __shared__ unsigned short Bls[128 * 128];
    char* Ac = (char*)Als;
    char* Bc = (char*)Bls;

    int z = blockIdx.y;
    int r0 = blockIdx.x * 64;
    int tid = threadIdx.x;
    int wave = tid >> 6, lane = tid & 63;

    const char* Wsrc = (const char*)(Wb + (size_t)z * 16384);

    #pragma unroll
    for (int p = 0; p < 4; ++p) {
        int o = p * 4096 + tid * 16;
        int r = o >> 8;
        int gr = r0 + r; if (gr >= M) gr = M - 1;
        uint4 v = *(const uint4*)((const char*)Xb + (size_t)gr * 256 + (o & 255));
        *(uint4*)(Ac + r * 256 + ((o & 255) ^ ((r & 7) << 4))) = v;
    }
    #pragma unroll
    for (int p = 0; p < 8; ++p) {
        int o = p * 4096 + tid * 16;
        int r = o >> 8;
        uint4 v = *(const uint4*)(Wsrc + o);
        *(uint4*)(Bc + (o ^ ((r & 7) << 4))) = v;
    }
    __syncthreads();

    fvec4 acc[8] = {};
    int arow = wave * 16 + (lane & 15);
    int kchunk = (lane >> 4) * 16;

    #pragma unroll
    for (int ks = 0; ks < 4; ++ks) {
        int ain = (ks * 64 + kchunk) ^ ((arow & 7) << 4);
        sv8 af = *(const sv8*)(Ac + arow * 256 + ain);
        #pragma unroll
        for (int cf = 0; cf < 8; ++cf) {
            int brow = cf * 16 + (lane & 15);
            int bin = (ks * 64 + kchunk) ^ ((brow & 7) << 4);
            sv8 bf = *(const sv8*)(Bc + brow * 256 + bin);
            acc[cf] = __builtin_amdgcn_mfma_f32_16x16x32_bf16(af, bf, acc[cf], 0, 0, 0);
        }
    }

    const float* bias = (z == 0) ? bq : (z == 1) ? bk : bv;

    #pragma unroll
    for (int cf = 0; cf < 8; ++cf) {
        int col_ = cf * 16 + (lane & 15);
        float b = bias[col_];
        #pragma unroll
        for (int r = 0; r < 4; ++r) {
            int gr = r0 + wave * 16 + ((lane >> 4) * 4) + r;
            if (gr < M) {
                float val = acc[cf][r] + b;
                if (z == 0) {
                    Qb[(size_t)gr * 128 + col_] = f2bf(val);
                } else if (z == 1) {
                    KVb[(size_t)gr * KVROW + col_] = f2fp8(val);   // K: byte = col
                } else {
                    int boff = 128 + ((col_ & 8) << 4) + ((col_ >> 4) << 4) + ((col_ & 7) << 1);
                    *(unsigned short*)(KVb + (size_t)gr * KVROW + boff) = f2bf(val);
                }
            }
        }
    }
}

// ---------------------------------------------------------------------------
// output projection via bf16 MFMA: out f32 = aggb bf16 @ Wo^T bf16 + bo
// ---------------------------------------------------------------------------
__global__ __launch_bounds__(256) void gemm_out(const unsigned short* __restrict__ Ab,
                                                const unsigned short* __restrict__ Wob,
                                                const float* __restrict__ bo,
                                                float* __restrict__ outp, int M) {
    __shared__ unsigned short Als[64 * 128];
    __shared__ unsigned short Bls[128 * 128];
    char* Ac = (char*)Als;
    char* Bc = (char*)Bls;

    int r0 = blockIdx.x * 64;
    int tid = threadIdx.x;
    int wave = tid >> 6, lane = tid & 63;

    #pragma unroll
    for (int p = 0; p < 4; ++p) {
        int o = p * 4096 + tid * 16;
        int r = o >> 8;
        int gr = r0 + r; if (gr >= M) gr = M - 1;
        uint4 v = *(const uint4*)((const char*)Ab + (size_t)gr * 256 + (o & 255));
        *(uint4*)(Ac + r * 256 + ((o & 255) ^ ((r & 7) << 4))) = v;
    }
    #pragma unroll
    for (int p = 0; p < 8; ++p) {
        int o = p * 4096 + tid * 16;
        int r = o >> 8;
        uint4 v = *(const uint4*)((const char*)Wob + o);
        *(uint4*)(Bc + (o ^ ((r & 7) << 4))) = v;
    }
    __syncthreads();

    fvec4 acc[8] = {};
    int arow = wave * 16 + (lane & 15);
    int kchunk = (lane >> 4) * 16;

    #pragma unroll
    for (int ks = 0; ks < 4; ++ks) {
        int ain = (ks * 64 + kchunk) ^ ((arow & 7) << 4);
        sv8 af = *(const sv8*)(Ac + arow * 256 + ain);
        #pragma unroll
        for (int cf = 0; cf < 8; ++cf) {
            int brow = cf * 16 + (lane & 15);
            int bin = (ks * 64 + kchunk) ^ ((brow & 7) << 4);
            sv8 bf = *(const sv8*)(Bc + brow * 256 + bin);
            acc[cf] = __builtin_amdgcn_mfma_f32_16x16x32_bf16(af, bf, acc[cf], 0, 0, 0);
        }
    }

    #pragma unroll
    for (int cf = 0; cf < 8; ++cf) {
        int col = cf * 16 + (lane & 15);
        float b = bo[col];
        #pragma unroll
        for (int r = 0; r < 4; ++r) {
            int gr = r0 + wave * 16 + ((lane >> 4) * 4) + r;
            if (gr < M) outp[(size_t)gr * 128 + col] = acc[cf][r] + b;
        }
    }
}

// ---------------------------------------------------------------------------
// CSR build: histogram -> 3-phase parallel scan
// ---------------------------------------------------------------------------
__global__ __launch_bounds__(256) void hist_kernel(const int* __restrict__ row,
                                                   int* __restrict__ cnt) {
    int e = blockIdx.x * 256 + threadIdx.x;
    if (e < NEDGES) atomicAdd(&cnt[row[e]], 1);
}

__global__ __launch_bounds__(256) void scan1_kernel(const int* __restrict__ cnt,
                                                    int* __restrict__ bsum) {
    __shared__ int red[256];
    int idx = blockIdx.x * 256 + threadIdx.x;
    red[threadIdx.x] = (idx < NNODES) ? cnt[idx] : 0;
    __syncthreads();
    for (int off = 128; off > 0; off >>= 1) {
        if (threadIdx.x < off) red[threadIdx.x] += red[threadIdx.x + off];
        __syncthreads();
    }
    if (threadIdx.x == 0) bsum[blockIdx.x] = red[0];
}

__global__ __launch_bounds__(256) void scan2_kernel(const int* __restrict__ bsum,
                                                    int* __restrict__ bpre) {
    __shared__ int ps[256];
    int t = threadIdx.x;
    int v = (t < NSB) ? bsum[t] : 0;
    ps[t] = v;
    __syncthreads();
    for (int off = 1; off < 256; off <<= 1) {
        int x = (t >= off) ? ps[t - off] : 0;
        __syncthreads();
        ps[t] += x;
        __syncthreads();
    }
    if (t < NSB) bpre[t] = ps[t] - v;   // exclusive block prefix
}

__global__ __launch_bounds__(256) void scan3_kernel(const int* __restrict__ cnt,
                                                    const int* __restrict__ bpre,
                                                    int* __restrict__ offs,
                                                    int* __restrict__ cursor) {
    __shared__ int ps[256];
    int t = threadIdx.x;
    int idx = blockIdx.x * 256 + t;
    int v = (idx < NNODES) ? cnt[idx] : 0;
    ps[t] = v;
    __syncthreads();
    for (int off = 1; off < 256; off <<= 1) {
        int x = (t >= off) ? ps[t - off] : 0;
        __syncthreads();
        ps[t] += x;
        __syncthreads();
    }
    int ex = ps[t] - v + bpre[blockIdx.x];
    if (idx < NNODES) { offs[idx] = ex; cursor[idx] = ex; }
    if (idx == NNODES) offs[NNODES] = NEDGES;
}

// ---------------------------------------------------------------------------
// FUSED score kernel (edge order — ef stays a pure HBM STREAM):
// 8 lanes per edge, lane s = head s. Per edge:
//   - s==0 claims CSR slot (atomicAdd), writes col_perm, broadcasts pos
//   - ef row streamed (4 x fvec4/lane, nontemporal, coalesced)
//   - Q[row] gather: lane s reads 32B (head s dims) — 256B contiguous/edge
//   - K[col] fp8 gather: lane s reads 16B — 128B contiguous/edge
//   - dot_s lane-local; ef·We partials + 3-step allreduce -> eb_s
//   - scores[pos*8+s] = dot_s*SCALE + eb_s  (f32, CSR order)
// QK gather latency hides in this kernel's HBM-stream slack.
// ---------------------------------------------------------------------------
__global__ __launch_bounds__(256) void score_scatter(const float* __restrict__ EF,
                                                     const int* __restrict__ row,
                                                     const int* __restrict__ col,
                                                     int* __restrict__ cursor,
                                                     const float* __restrict__ We,
                                                     const float* __restrict__ be,
                                                     const unsigned short* __restrict__ Qb,
                                                     const unsigned char* __restrict__ KVb,
                                                     float* __restrict__ scores,
                                                     int* __restrict__ col_perm) {
    __shared__ float sWe[8][128];   // [h][d]
    __shared__ float sbe[8];
    for (int i = threadIdx.x; i < 1024; i += 256) {
        int d = i >> 3, h = i & 7;
        sWe[h][d] = We[i];          // We is [d][h] row-major
    }
    if (threadIdx.x < 8) sbe[threadIdx.x] = be[threadIdx.x];
    __syncthreads();

    int g = blockIdx.x * 256 + threadIdx.x;   // NEDGES*8 threads
    int e = g >> 3;
    int s = g & 7;
    if (e >= NEDGES) return;
    int lane = threadIdx.x & 63;

    int r = row[e];
    int c = col[e];

    // claim CSR slot early (latency hides under the streams/gathers below)
    int pos = 0;
    if (s == 0) {
        pos = atomicAdd(&cursor[r], 1);
        col_perm[pos] = c;
    }

    // issue gathers early: Q head-slice (32B) + K fp8 head-slice (16B)
    const uint4* qp = (const uint4*)(Qb + (size_t)r * 128 + s * 16);
    uint4 qu0 = qp[0], qu1 = qp[1];
    uint4 ku = *(const uint4*)(KVb + (size_t)c * KVROW + s * 16);

    const fvec4* efv = (const fvec4*)(EF + (size_t)e * 128);
    float acc[8] = {0.f, 0.f, 0.f, 0.f, 0.f, 0.f, 0.f, 0.f};
    #pragma unroll
    for (int i = 0; i < 4; ++i) {
        int d4 = s + 8 * i;
        fvec4 v = __builtin_nontemporal_load(&efv[d4]);
        #pragma unroll
        for (int h = 0; h < 8; ++h) {
            fvec4 w = *(const fvec4*)&sWe[h][d4 * 4];
            acc[h] += v.x * w.x + v.y * w.y + v.z * w.z + v.w * w.w;
        }
    }

    #pragma unroll
    for (int off = 1; off < 8; off <<= 1)
        #pragma unroll
        for (int h = 0; h < 8; ++h)
            acc[h] += __shfl_xor(acc[h], off);

    // lane-local QK dot for head s
    fvec4 q0, q1, q2, q3, k0, k1, k2, k3;
    bf8_to_f32(qu0, q0, q1);
    bf8_to_f32(qu1, q2, q3);
    fp8x4_to_f32(ku.x, k0);
    fp8x4_to_f32(ku.y, k1);
    fp8x4_to_f32(ku.z, k2);
    fp8x4_to_f32(ku.w, k3);
    fvec4 d4v = q0 * k0 + q1 * k1 + q2 * k2 + q3 * k3;
    float dot = d4v.x + d4v.y + d4v.z + d4v.w;

    pos = __shfl(pos, lane & ~7);             // broadcast from the group's s==0 lane
    scores[(size_t)pos * 8 + s] = dot * QK_SCALE + acc[s] + sbe[s];
}

// ---------------------------------------------------------------------------
// fused online segment softmax + PV. Per slot-edge: f32 score (coalesced),
// col_perm, 2 V gathers (bf16, part-interleaved). No K/Q/ef access.
// ---------------------------------------------------------------------------
__global__ __launch_bounds__(256) void fused_agg(const float* __restrict__ scores,
                                                 const unsigned char* __restrict__ KV,
                                                 const int* __restrict__ col_perm,
                                                 const int* __restrict__ offs,
                                                 unsigned short* __restrict__ aggb) {
    int node = blockIdx.x * 4 + (threadIdx.x >> 6);
    if (node >= NNODES) return;
    int lane = threadIdx.x & 63;
    int slot = lane >> 3;
    int h    = lane & 7;
    int start = offs[node];
    int end   = offs[node + 1];

    float m = -3.0e38f;
    float sum = 0.0f;
    fvec4 a0 = {0.f,0.f,0.f,0.f}, a1 = {0.f,0.f,0.f,0.f};
    fvec4 a2 = {0.f,0.f,0.f,0.f}, a3 = {0.f,0.f,0.f,0.f};

    for (int i = start + slot; i < end; i += 8) {
        int c = col_perm[i];
        float s = scores[(size_t)i * 8 + h];
        const uint4* kp = (const uint4*)(KV + (size_t)c * KVROW);
        uint4 vu0 = kp[8 + h];      // V part0 (bf16)
        uint4 vu1 = kp[16 + h];     // V part1 (bf16)
        fvec4 v0, v1, v2, v3;
        bf8_to_f32(vu0, v0, v1);
        bf8_to_f32(vu1, v2, v3);

        float mn = fmaxf(m, s);
        float corr = __expf(m - mn);
        float w = __expf(s - mn);
        sum = sum * corr + w;
        a0 = a0 * corr + w * v0;
        a1 = a1 * corr + w * v1;
        a2 = a2 * corr + w * v2;
        a3 = a3 * corr + w * v3;
        m = mn;
    }

    #pragma unroll
    for (int off = 8; off < 64; off <<= 1) {
        float mo = __shfl_xor(m, off);
        float so = __shfl_xor(sum, off);
        fvec4 b0, b1, b2, b3;
        b0.x = __shfl_xor(a0.x, off); b0.y = __shfl_xor(a0.y, off);
        b0.z = __shfl_xor(a0.z, off); b0.w = __shfl_xor(a0.w, off);
        b1.x = __shfl_xor(a1.x, off); b1.y = __shfl_xor(a1.y, off);
        b1.z = __shfl_xor(a1.z, off); b1.w = __shfl_xor(a1.w, off);
        b2.x = __shfl_xor(a2.x, off); b2.y = __shfl_xor(a2.y, off);
        b2.z = __shfl_xor(a2.z, off); b2.w = __shfl_xor(a2.w, off);
        b3.x = __shfl_xor(a3.x, off); b3.y = __shfl_xor(a3.y, off);
        b3.z = __shfl_xor(a3.z, off); b3.w = __shfl_xor(a3.w, off);
        float M = fmaxf(m, mo);
        float c1 = __expf(m - M);
        float c2 = __expf(mo - M);
        sum = sum * c1 + so * c2;
        a0 = a0 * c1 + b0 * c2;
        a1 = a1 * c1 + b1 * c2;
        a2 = a2 * c1 + b2 * c2;
        a3 = a3 * c1 + b3 * c2;
        m = M;
    }

    if (slot == 0) {
        float inv = (sum > 0.0f) ? (1.0f / sum) : 0.0f;
        unsigned short* op = aggb + (size_t)node * 128 + h * 16;
        ushort4 s;
        s.x = f2bf(a0.x * inv); s.y = f2bf(a0.y * inv); s.z = f2bf(a0.z * inv); s.w = f2bf(a0.w * inv);
        *(ushort4*)(op + 0) = s;
        s.x = f2bf(a1.x * inv); s.y = f2bf(a1.y * inv); s.z = f2bf(a1.z * inv); s.w = f2bf(a1.w * inv);
        *(ushort4*)(op + 4) = s;
        s.x = f2bf(a2.x * inv); s.y = f2bf(a2.y * inv); s.z = f2bf(a2.z * inv); s.w = f2bf(a2.w * inv);
        *(ushort4*)(op + 8) = s;
        s.x = f2bf(a3.x * inv); s.y = f2bf(a3.y * inv); s.z = f2bf(a3.z * inv); s.w = f2bf(a3.w * inv);
        *(ushort4*)(op + 12) = s;
    }
}

// ---------------------------------------------------------------------------
extern "C" void kernel_launch(void* const* d_in, const int* in_sizes, int n_in,
                              void* d_out, int out_size, void* d_ws, size_t ws_size,
                              hipStream_t stream) {
    const float* node = (const float*)d_in[0];
    const int*   ei   = (const int*)d_in[1];
    const float* ef   = (const float*)d_in[2];
    const float* Wq   = (const float*)d_in[3];
    const float* bq   = (const float*)d_in[4];
    const float* Wk   = (const float*)d_in[5];
    const float* bk   = (const float*)d_in[6];
    const float* Wv   = (const float*)d_in[7];
    const float* bv   = (const float*)d_in[8];
    const float* We   = (const float*)d_in[9];
    const float* be   = (const float*)d_in[10];
    const float* Wo   = (const float*)d_in[11];
    const float* bo   = (const float*)d_in[12];
    float* out = (float*)d_out;

    const int* row = ei;
    const int* col = ei + NEDGES;

    // workspace layout (all 16B-aligned)
    unsigned short* Qb   = (unsigned short*)d_ws;                 // NNODES*128 bf16
    unsigned char*  KVb  = (unsigned char*)(Qb + (size_t)NNODES * 128); // NNODES*384 B
    unsigned short* Xb   = (unsigned short*)(KVb + (size_t)NNODES * KVROW); // NNODES*128 bf16
    unsigned short* Wb   = Xb  + (size_t)NNODES * 128;            // 4*16384 bf16
    unsigned short* aggb = Wb  + 4 * 16384;                       // NNODES*128 bf16
    float* scores  = (float*)(aggb + (size_t)NNODES * 128);       // NEDGES*8 f32 (CSR order)
    int*   cnt      = (int*)(scores + (size_t)NEDGES * 8);        // NNODES
    int*   offs     = cnt + NNODES;                               // NNODES+1
    int*   cursor   = offs + NNODES + 1;                          // NNODES
    int*   col_perm = cursor + NNODES;                            // NEDGES
    int*   bsum     = col_perm + NEDGES;                          // 256
    int*   bpre     = bsum + 256;                                 // 256

    prep_kernel<<<(NNODES * 32 + 4 * 16384 + NNODES + 255) / 256, 256, 0, stream>>>(
        node, Wq, Wk, Wv, Wo, Xb, Wb, cnt);
    hist_kernel<<<(NEDGES + 255) / 256, 256, 0, stream>>>(row, cnt);
    scan1_kernel<<<NSB, 256, 0, stream>>>(cnt, bsum);
    scan2_kernel<<<1, 256, 0, stream>>>(bsum, bpre);
    scan3_kernel<<<NSB, 256, 0, stream>>>(cnt, bpre, offs, cursor);

    dim3 gqkv((NNODES + 63) / 64, 3);
    gemm_qkv<<<gqkv, 256, 0, stream>>>(Xb, Wb, bq, bk, bv, Qb, KVb, NNODES);

    score_scatter<<<NEDGES * 8 / 256, 256, 0, stream>>>(ef, row, col, cursor, We, be,
                                                        Qb, KVb, scores, col_perm);

    fused_agg<<<(NNODES + 3) / 4, 256, 0, stream>>>(scores, KVb, col_perm, offs, aggb);

    gemm_out<<<(NNODES + 63) / 64, 256, 0, stream>>>(aggb, Wb + 3 * 16384, bo, out, NNODES);
}